// Round 3
// baseline (15741.508 us; speedup 1.0000x reference)
//
#include <hip/hip_runtime.h>

#define TT 512
#define BB 64
#define HH 1024
#define G4 4096

typedef _Float16 h8 __attribute__((ext_vector_type(8)));
typedef float f4 __attribute__((ext_vector_type(4)));
typedef unsigned long long u64;

// ---------------- prep kernels ----------------

// W_ih fp32 -> fp16, flat copy. 4096*1024 elems, 8 per thread.
__global__ void k_conv_wih(const float* __restrict__ w, _Float16* __restrict__ o) {
  int i = blockIdx.x * 256 + threadIdx.x;
  const f4* src = (const f4*)w + (size_t)i * 2;
  f4 a = src[0], b = src[1];
  h8 r;
  r[0] = (_Float16)a[0]; r[1] = (_Float16)a[1]; r[2] = (_Float16)a[2]; r[3] = (_Float16)a[3];
  r[4] = (_Float16)b[0]; r[5] = (_Float16)b[1]; r[6] = (_Float16)b[2]; r[7] = (_Float16)b[3];
  *(h8*)(o + (size_t)i * 8) = r;
}

// W_hh fp32 [4096,1024] -> fp16 shuffled into MFMA B-fragment order:
// block b = nblk*32 + kblk holds lane l: W[nblk*16 + (l&15)][kblk*32 + (l>>4)*8 + j].
__global__ void k_shuf_whh(const float* __restrict__ w, _Float16* __restrict__ o) {
  int cidx = blockIdx.x * 256 + threadIdx.x;
  int b = cidx >> 6;
  int lid = cidx & 63;
  int n = (b >> 5) * 16 + (lid & 15);
  int k0 = (b & 31) * 32 + (lid >> 4) * 8;
  const float* src = w + (size_t)n * HH + k0;
  h8 r;
  #pragma unroll
  for (int j = 0; j < 8; ++j) r[j] = (_Float16)src[j];
  *(h8*)(o + (size_t)b * 512 + lid * 8) = r;
}

__global__ void k_bsum(const float* __restrict__ bi, const float* __restrict__ bh,
                       float* __restrict__ o) {
  int i = blockIdx.x * 256 + threadIdx.x;
  o[i] = bi[i] + bh[i];
}

// h0 fp32 -> fp16 into hbuf[0]; zero the grid barrier.
__global__ void k_prep(const float* __restrict__ h0, _Float16* __restrict__ hbuf,
                       unsigned* __restrict__ bar) {
  int i = blockIdx.x * 256 + threadIdx.x;
  hbuf[i] = (_Float16)h0[i];
  if (i == 0) { bar[0] = 0u; bar[64] = 0u; }
}

// ---------------- phase A: gates_x = x @ W_ih^T + (b_ih + b_hh) ----------------
// Output layout re-shuffled for phase B: gx[((t*64 + s)*4 + g)*1024 + b*16 + j]
// where n = g*1024 + s*16 + j, row = t*64 + b.
__global__ __launch_bounds__(256) void k_gemm_gx(
    const float* __restrict__ x, const _Float16* __restrict__ wih,
    const float* __restrict__ bsum, _Float16* __restrict__ gx) {
  __shared__ _Float16 As[128 * 40];
  __shared__ _Float16 Bs[128 * 40];
  const int bid = blockIdx.x;
  const int m0 = (bid >> 5) * 128;
  const int n0 = (bid & 31) * 128;
  const int tid = threadIdx.x;
  const int w = tid >> 6, l = tid & 63, q = l >> 4, lj = l & 15;
  const int wm = (w >> 1) * 64, wn = (w & 1) * 64;
  const int lrow = tid >> 1;
  const int lcol = (tid & 1) * 16;

  f4 z = {0.f, 0.f, 0.f, 0.f};
  f4 acc[4][4];
  #pragma unroll
  for (int i2 = 0; i2 < 4; ++i2)
    #pragma unroll
    for (int j2 = 0; j2 < 4; ++j2) acc[i2][j2] = z;

  for (int kt = 0; kt < 32; ++kt) {
    const int k0 = kt * 32;
    const float* xp = x + (size_t)(m0 + lrow) * HH + k0 + lcol;
    f4 a0 = ((const f4*)xp)[0];
    f4 a1 = ((const f4*)xp)[1];
    f4 a2 = ((const f4*)xp)[2];
    f4 a3 = ((const f4*)xp)[3];
    const _Float16* bp = wih + (size_t)(n0 + lrow) * HH + k0 + lcol;
    h8 b0 = ((const h8*)bp)[0];
    h8 b1 = ((const h8*)bp)[1];
    h8 lo, hi;
    lo[0] = (_Float16)a0[0]; lo[1] = (_Float16)a0[1]; lo[2] = (_Float16)a0[2]; lo[3] = (_Float16)a0[3];
    lo[4] = (_Float16)a1[0]; lo[5] = (_Float16)a1[1]; lo[6] = (_Float16)a1[2]; lo[7] = (_Float16)a1[3];
    hi[0] = (_Float16)a2[0]; hi[1] = (_Float16)a2[1]; hi[2] = (_Float16)a2[2]; hi[3] = (_Float16)a2[3];
    hi[4] = (_Float16)a3[0]; hi[5] = (_Float16)a3[1]; hi[6] = (_Float16)a3[2]; hi[7] = (_Float16)a3[3];
    __syncthreads();
    *(h8*)&As[lrow * 40 + lcol] = lo;
    *(h8*)&As[lrow * 40 + lcol + 8] = hi;
    *(h8*)&Bs[lrow * 40 + lcol] = b0;
    *(h8*)&Bs[lrow * 40 + lcol + 8] = b1;
    __syncthreads();
    h8 af[4], bf[4];
    #pragma unroll
    for (int mt = 0; mt < 4; ++mt) af[mt] = *(h8*)&As[(wm + mt * 16 + lj) * 40 + q * 8];
    #pragma unroll
    for (int nt = 0; nt < 4; ++nt) bf[nt] = *(h8*)&Bs[(wn + nt * 16 + lj) * 40 + q * 8];
    #pragma unroll
    for (int mt = 0; mt < 4; ++mt)
      #pragma unroll
      for (int nt = 0; nt < 4; ++nt)
        acc[mt][nt] = __builtin_amdgcn_mfma_f32_16x16x32_f16(af[mt], bf[nt], acc[mt][nt], 0, 0, 0);
  }
  #pragma unroll
  for (int nt = 0; nt < 4; ++nt) {
    int n = n0 + wn + nt * 16 + lj;
    float bv = bsum[n];
    int g = n >> 10, rem = n & 1023, sc = rem >> 4, j = rem & 15;
    #pragma unroll
    for (int mt = 0; mt < 4; ++mt) {
      #pragma unroll
      for (int r = 0; r < 4; ++r) {
        int row = m0 + wm + mt * 16 + q * 4 + r;
        int tt = row >> 6, b = row & 63;
        size_t addr = (((size_t)(tt * 64 + sc) * 4 + g) << 10) + b * 16 + j;
        __builtin_nontemporal_store((_Float16)(acc[mt][nt][r] + bv), &gx[addr]);
      }
    }
  }
}

// ---------------- phase B: persistent reverse scan ----------------
// 64 wgs (1/CU). wg s owns h-cols [16s,16s+16). Wave w owns k in [256w,+256),
// computes partial sums for ALL 4 gates; W slice (32KB/wave) lives in VGPRs.
// Partial-K reduce via LDS atomicAdd. h exchange via LLC-direct relaxed atomics
// (no cache-maintenance fences anywhere). c stays in registers.
__global__ __launch_bounds__(256, 1) void k_lstm_seq(
    const _Float16* __restrict__ gx, const _Float16* __restrict__ wsh,
    const float* __restrict__ c0, float* __restrict__ out,
    _Float16* __restrict__ hbuf, unsigned* __restrict__ bar) {
  __shared__ float gbuf[4096];   // [g][m 64][j 16] f32, 16 KB
  const int tid = threadIdx.x;
  const int s = blockIdx.x;
  const int w = tid >> 6, l = tid & 63, q = l >> 4, lj = l & 15;

  #pragma unroll
  for (int u = 0; u < 16; ++u) gbuf[u * 256 + tid] = 0.f;

  // W_hh fragments resident in registers: [gate][kt] -> 32 x 16B = 128 VGPRs.
  h8 wreg[4][8];
  #pragma unroll
  for (int g = 0; g < 4; ++g)
    #pragma unroll
    for (int kt = 0; kt < 8; ++kt)
      wreg[g][kt] = *(const h8*)(wsh + (size_t)((g * 64 + s) * 32 + w * 8 + kt) * 512 + l * 8);

  // elementwise mapping: thread tid -> m = (tid>>4)+16r (r=0..3), j = tid&15
  const int em = tid >> 4;
  const int ej = tid & 15;
  float cv[4];
  #pragma unroll
  for (int r = 0; r < 4; ++r)
    cv[r] = c0[(size_t)(em + 16 * r) * HH + s * 16 + ej];

  __syncthreads();

  for (int ii = 0; ii < TT; ++ii) {
    const int t = TT - 1 - ii;
    const _Float16* __restrict__ hcur = hbuf + (size_t)(ii & 1) * (BB * HH);
    _Float16* __restrict__ hnxt = hbuf + (size_t)((ii + 1) & 1) * (BB * HH);

    // gx prefetch: contiguous per-wg 8KB slab, consumed only at elementwise.
    const _Float16* gxb = gx + ((size_t)(t * 64 + s) * 4) * 1024 + tid;
    _Float16 gxl[16];
    #pragma unroll
    for (int g = 0; g < 4; ++g)
      #pragma unroll
      for (int r = 0; r < 4; ++r)
        gxl[g * 4 + r] = __builtin_nontemporal_load(gxb + g * 1024 + r * 256);

    f4 z = {0.f, 0.f, 0.f, 0.f};
    f4 acc[4][4];
    #pragma unroll
    for (int g = 0; g < 4; ++g)
      #pragma unroll
      for (int mt = 0; mt < 4; ++mt) acc[g][mt] = z;

    // software-pipelined LLC-direct h loads (distance 2), fully unrolled.
    u64 pl[2][4], ph[2][4];
    auto issue = [&](int kt, int st) {
      #pragma unroll
      for (int mt = 0; mt < 4; ++mt) {
        const u64* p = (const u64*)(hcur + (size_t)(mt * 16 + lj) * HH + (w * 8 + kt) * 32 + q * 8);
        pl[st][mt] = __hip_atomic_load(p, __ATOMIC_RELAXED, __HIP_MEMORY_SCOPE_AGENT);
        ph[st][mt] = __hip_atomic_load(p + 1, __ATOMIC_RELAXED, __HIP_MEMORY_SCOPE_AGENT);
      }
    };
    issue(0, 0);
    issue(1, 1);
    #pragma unroll
    for (int kt = 0; kt < 8; ++kt) {
      const int st = kt & 1;
      h8 afr[4];
      #pragma unroll
      for (int mt = 0; mt < 4; ++mt) {
        union { u64 u[2]; h8 v; } tmp;
        tmp.u[0] = pl[st][mt]; tmp.u[1] = ph[st][mt];
        afr[mt] = tmp.v;
      }
      if (kt < 6) issue(kt + 2, st);
      #pragma unroll
      for (int g = 0; g < 4; ++g)
        #pragma unroll
        for (int mt = 0; mt < 4; ++mt)
          acc[g][mt] = __builtin_amdgcn_mfma_f32_16x16x32_f16(afr[mt], wreg[g][kt], acc[g][mt], 0, 0, 0);
    }

    // partial-K reduce: C-layout row = mt*16+q*4+r (batch), col = lj.
    #pragma unroll
    for (int g = 0; g < 4; ++g)
      #pragma unroll
      for (int mt = 0; mt < 4; ++mt)
        #pragma unroll
        for (int r = 0; r < 4; ++r)
          atomicAdd(&gbuf[g * 1024 + (mt * 16 + q * 4 + r) * 16 + lj], acc[g][mt][r]);
    __syncthreads();

    // elementwise: thread tid handles (m = em+16r, j = ej); gbuf idx = g*1024 + r*256 + tid.
    #pragma unroll
    for (int r = 0; r < 4; ++r) {
      const int m = em + 16 * r;
      float gi = gbuf[0 * 1024 + r * 256 + tid] + (float)gxl[0 * 4 + r];
      float gf = gbuf[1 * 1024 + r * 256 + tid] + (float)gxl[1 * 4 + r];
      float gg = gbuf[2 * 1024 + r * 256 + tid] + (float)gxl[2 * 4 + r];
      float go = gbuf[3 * 1024 + r * 256 + tid] + (float)gxl[3 * 4 + r];
      float iv = 1.f / (1.f + __expf(-gi));
      float fv = 1.f / (1.f + __expf(-gf));
      float gv = 2.f / (1.f + __expf(-2.f * gg)) - 1.f;
      float ov = 1.f / (1.f + __expf(-go));
      float cn = fv * cv[r] + iv * gv;
      float hn = ov * (2.f / (1.f + __expf(-2.f * cn)) - 1.f);
      cv[r] = cn;
      __builtin_nontemporal_store(hn, &out[((size_t)t * BB + m) * HH + s * 16 + ej]);
      unsigned short hb = __builtin_bit_cast(unsigned short, (_Float16)hn);
      __hip_atomic_store((unsigned short*)(hnxt + (size_t)m * HH + s * 16 + ej), hb,
                         __ATOMIC_RELAXED, __HIP_MEMORY_SCOPE_AGENT);
      if (t == 0) {
        out[(size_t)TT * BB * HH + (size_t)m * HH + s * 16 + ej] = hn;
        out[(size_t)TT * BB * HH + (size_t)BB * HH + (size_t)m * HH + s * 16 + ej] = cn;
      }
    }
    // re-zero gbuf for next step (each thread zeros exactly what it read).
    #pragma unroll
    for (int g = 0; g < 4; ++g)
      #pragma unroll
      for (int r = 0; r < 4; ++r) gbuf[g * 1024 + r * 256 + tid] = 0.f;

    // grid barrier, fence-free: __syncthreads drains vmcnt (h-stores at LLC),
    // relaxed RMW arrive + relaxed poll; h loads next step are LLC-direct.
    __syncthreads();
    if (tid == 0) {
      unsigned old = __hip_atomic_fetch_add(&bar[0], 1u, __ATOMIC_RELAXED, __HIP_MEMORY_SCOPE_AGENT);
      if (old == 64u * (unsigned)(ii + 1) - 1u) {
        __hip_atomic_store(&bar[64], (unsigned)(ii + 1), __ATOMIC_RELAXED, __HIP_MEMORY_SCOPE_AGENT);
      } else {
        while (__hip_atomic_load(&bar[64], __ATOMIC_RELAXED, __HIP_MEMORY_SCOPE_AGENT) <
               (unsigned)(ii + 1)) {
          __builtin_amdgcn_s_sleep(1);
        }
      }
    }
    __syncthreads();
  }
}

// ---------------- launch ----------------
extern "C" void kernel_launch(void* const* d_in, const int* in_sizes, int n_in,
                              void* d_out, int out_size, void* d_ws, size_t ws_size,
                              hipStream_t stream) {
  const float* x    = (const float*)d_in[0];
  const float* h0   = (const float*)d_in[1];
  const float* c0   = (const float*)d_in[2];
  const float* W_ih = (const float*)d_in[3];
  const float* W_hh = (const float*)d_in[4];
  const float* b_ih = (const float*)d_in[5];
  const float* b_hh = (const float*)d_in[6];
  float* out = (float*)d_out;

  char* ws = (char*)d_ws;
  size_t off = 0;
  auto take = [&](size_t bytes) -> void* {
    void* p = ws + off;
    off = (off + bytes + 255) & ~(size_t)255;
    return p;
  };
  _Float16* gx    = (_Float16*)take((size_t)TT * BB * G4 * 2);  // 268 MB
  _Float16* wih_h = (_Float16*)take((size_t)G4 * HH * 2);       // 8.4 MB
  _Float16* wsh   = (_Float16*)take((size_t)G4 * HH * 2);       // 8.4 MB
  float*    bsum  = (float*)take((size_t)G4 * 4);
  _Float16* hbuf  = (_Float16*)take((size_t)2 * BB * HH * 2);   // ping-pong h
  unsigned* bar   = (unsigned*)take(512);
  if (off > ws_size) return;

  k_conv_wih<<<2048, 256, 0, stream>>>(W_ih, wih_h);
  k_shuf_whh<<<2048, 256, 0, stream>>>(W_hh, wsh);
  k_bsum<<<16, 256, 0, stream>>>(b_ih, b_hh, bsum);
  k_prep<<<256, 256, 0, stream>>>(h0, hbuf, bar);
  k_gemm_gx<<<8192, 256, 0, stream>>>(x, wih_h, bsum, gx);
  k_lstm_seq<<<64, 256, 0, stream>>>(gx, wsh, c0, out, hbuf, bar);
}